// Round 15
// baseline (439.983 us; speedup 1.0000x reference)
//
#include <hip/hip_runtime.h>

#define D_FEAT 64
#define CHUNK 8192
#define BSHIFT 9
#define BSIZE 512
#define NPW 8
#define TSHIFT 14                  // src tile = src >> 14 (7 live tiles for N=100000)
#define NTILES 7

typedef unsigned int uint;
typedef unsigned short ushort;
typedef unsigned char uchar;

static __device__ __forceinline__ ushort f2bf(float f) {
    uint u = __float_as_uint(f);
    uint r = (u + 0x7fffu + ((u >> 16) & 1u)) >> 16;   // RNE
    return (ushort)r;
}
static __device__ __forceinline__ float bf2f(ushort b) {
    return __uint_as_float(((uint)b) << 16);
}
static __device__ __forceinline__ float wq2f(uint ev) {
    return (float)(ev & 32767u) * (1.0f / 32768.0f) + (1.0f / 65536.0f);
}

// ---------- Phase A: bucket histogram (bucket = dst >> 9), int4 reads ----------
__global__ void bucket_hist(const int* __restrict__ dst, int* __restrict__ bcount, int n_edges) {
    __shared__ int h[256];
    h[threadIdx.x] = 0;
    __syncthreads();
    int tid = blockIdx.x * blockDim.x + threadIdx.x;
    int stride = gridDim.x * blockDim.x;
    int n4 = n_edges >> 2;
    for (int i = tid; i < n4; i += stride) {
        int4 d = ((const int4*)dst)[i];
        atomicAdd(&h[d.x >> BSHIFT], 1);
        atomicAdd(&h[d.y >> BSHIFT], 1);
        atomicAdd(&h[d.z >> BSHIFT], 1);
        atomicAdd(&h[d.w >> BSHIFT], 1);
    }
    for (int i = (n4 << 2) + tid; i < n_edges; i += stride)
        atomicAdd(&h[dst[i] >> BSHIFT], 1);
    __syncthreads();
    int v = h[threadIdx.x];
    if (v) atomicAdd(&bcount[threadIdx.x], v);
}

// ---------- Phase C: staged counting sort by bucket; packed 6B planes, local bbase scan ----------
__global__ __launch_bounds__(256) void partition_kernel(
        const int* __restrict__ src, const int* __restrict__ dst,
        const float* __restrict__ w, const int* __restrict__ bcount,
        int* __restrict__ bcursor,
        uint* __restrict__ interp, ushort* __restrict__ interd, int n_edges) {
    __shared__ int hist[256];
    __shared__ int lofs[256];
    __shared__ int cur[256];
    __shared__ int gbase[256];
    __shared__ int scn[256];
    __shared__ uint   bufp[CHUNK];       // 32 KB packed (src<<15)|wq
    __shared__ ushort bufd[CHUNK];       // 16 KB dstlo
    __shared__ uchar  bb[CHUNK];         //  8 KB bucket id
    int t = threadIdx.x;
    int beg = blockIdx.x * CHUNK;
    int end = min(beg + CHUNK, n_edges);
    int cnt = end - beg;

    hist[t] = 0;
    __syncthreads();
    for (int i = beg + t; i < end; i += 256)
        atomicAdd(&hist[dst[i] >> BSHIFT], 1);
    __syncthreads();
    int v = hist[t];
    scn[t] = v;
    __syncthreads();
    for (int off = 1; off < 256; off <<= 1) {
        int u = (t >= off) ? scn[t - off] : 0;
        __syncthreads();
        scn[t] += u;
        __syncthreads();
    }
    int excl = scn[t] - v;
    lofs[t] = excl;
    cur[t]  = excl;
    __syncthreads();
    for (int i = beg + t; i < end; i += 256) {
        int d = dst[i];
        int b = d >> BSHIFT;
        int p = atomicAdd(&cur[b], 1);
        float wf = w[i];
        uint wq = (uint)(wf * 32768.0f);
        if (wq > 32767u) wq = 32767u;
        bufp[p] = ((uint)src[i] << 15) | wq;
        bufd[p] = (ushort)(d & (BSIZE - 1));
        bb[p]   = (uchar)b;
    }
    __syncthreads();
    int bcv = bcount[t];
    scn[t] = bcv;
    __syncthreads();
    for (int off = 1; off < 256; off <<= 1) {
        int u = (t >= off) ? scn[t - off] : 0;
        __syncthreads();
        scn[t] += u;
        __syncthreads();
    }
    int gbb = scn[t] - bcv;
    if (hist[t]) gbase[t] = gbb + atomicAdd(&bcursor[t], hist[t]);
    __syncthreads();
    for (int i = t; i < cnt; i += 256) {
        int b = bb[i];
        int pos = gbase[b] + (i - lofs[b]);
        interp[pos] = bufp[i];
        interd[pos] = bufd[i];
    }
}

// ---------- Phase D: per-bucket counting sort on key (dstlo<<3)|srctile; emits tptr[8][N+1] ----------
// Plane 0 of tptr is row_ptr; plane t+1[node] = end of node's tile-t segment
// (bins per node are contiguous & tile-ascending; tile 7 is always empty so
//  plane 7[node] = end of node's edges).
__global__ __launch_bounds__(512) void finalize_kernel(
        const uint* __restrict__ interp, const ushort* __restrict__ interd,
        const int* __restrict__ bcount, uint* __restrict__ edges,
        int* __restrict__ tptr, int n_nodes, int n_edges) {
    __shared__ int hist[4096];           // 16 KB bins, reused as cursors
    __shared__ int scn[512];
    int b = blockIdx.x;
    int t = threadIdx.x;

    // bucket base via local scan of bcount
    if (t < 256) scn[t] = bcount[t];
    __syncthreads();
    for (int off = 1; off < 256; off <<= 1) {
        int u = (t < 256 && t >= off) ? scn[t - off] : 0;
        __syncthreads();
        if (t < 256) scn[t] += u;
        __syncthreads();
    }
    int base = (b == 0) ? 0 : scn[b - 1];
    int cnt  = scn[b] - base;
    __syncthreads();

    for (int i = t; i < 4096; i += 512) hist[i] = 0;
    __syncthreads();
    for (int i = t; i < cnt; i += 512) {
        uint p = interp[base + i];
        int key = ((int)interd[base + i] << 3) | (int)(p >> 29);   // (dstlo<<3)|tile
        atomicAdd(&hist[key], 1);
    }
    __syncthreads();
    // blocked exclusive scan over 4096 bins; thread t owns dlo=t (8 tile bins)
    int loc[8];
    int s = 0;
    #pragma unroll
    for (int k = 0; k < 8; ++k) { int v = hist[(t << 3) + k]; loc[k] = s; s += v; }
    scn[t] = s;
    __syncthreads();
    for (int off = 1; off < 512; off <<= 1) {
        int u = (t >= off) ? scn[t - off] : 0;
        __syncthreads();
        scn[t] += u;
        __syncthreads();
    }
    int excl = scn[t] - s;
    int node = (b << BSHIFT) + t;
    if (node < n_nodes) {
        #pragma unroll
        for (int k = 0; k < 8; ++k)
            tptr[k * (n_nodes + 1) + node] = base + excl + loc[k];
    }
    if (b == 0 && t == 0) tptr[n_nodes] = n_edges;   // plane-0 tail
    #pragma unroll
    for (int k = 0; k < 8; ++k) hist[(t << 3) + k] = excl + loc[k];
    __syncthreads();
    for (int i = t; i < cnt; i += 512) {
        uint p = interp[base + i];
        int key = ((int)interd[base + i] << 3) | (int)(p >> 29);
        int pos = atomicAdd(&hist[key], 1);
        edges[base + pos] = p;
    }
}

// ---------- convert: f32 features -> bf16, vectorized ----------
__global__ void cvt_bf16(const float* __restrict__ in, ushort* __restrict__ out, int n4) {
    int i = blockIdx.x * blockDim.x + threadIdx.x;
    int stride = gridDim.x * blockDim.x;
    for (; i < n4; i += stride) {
        float4 v = ((const float4*)in)[i];
        ushort4 o;
        o.x = f2bf(v.x); o.y = f2bf(v.y); o.z = f2bf(v.z); o.w = f2bf(v.w);
        ((ushort4*)out)[i] = o;
    }
}

// ---------- gather hop (R9 known-good): one wave per NPW nodes; lane = feature ----------
template <bool OUT_BF16>
__global__ __launch_bounds__(256) void gather_hop(
        const ushort* __restrict__ h, const uint* __restrict__ edges,
        const int* __restrict__ row_ptr, void* __restrict__ out_v, int n_nodes) {
    int wv = blockIdx.x * 4 + (threadIdx.x >> 6);
    int n0 = __builtin_amdgcn_readfirstlane(wv * NPW);
    if (n0 >= n_nodes) return;
    int f = threadIdx.x & 63;

    int rp[NPW + 1];
    #pragma unroll
    for (int i = 0; i <= NPW; ++i)
        rp[i] = row_ptr[min(n0 + i, n_nodes)];

    #pragma unroll
    for (int ni = 0; ni < NPW; ++ni) {
        int node = n0 + ni;
        if (node >= n_nodes) break;
        int beg = __builtin_amdgcn_readfirstlane(rp[ni]);
        int end = __builtin_amdgcn_readfirstlane(rp[ni + 1]);
        float acc = 0.0f;
        int j = beg;
        for (; j + 8 <= end; j += 8) {
            #pragma unroll
            for (int k = 0; k < 8; ++k) {
                uint ev = edges[j + k];
                acc += wq2f(ev) * bf2f(h[((size_t)(ev >> 15) << 6) + f]);
            }
        }
        for (; j < end; ++j) {
            uint ev = edges[j];
            acc += wq2f(ev) * bf2f(h[((size_t)(ev >> 15) << 6) + f]);
        }
        size_t o = ((size_t)node << 6) + f;
        if (OUT_BF16) ((ushort*)out_v)[o] = f2bf(acc);
        else          ((float*)out_v)[o]  = acc;
    }
}

// ---------- tiled gather (A/B on hop 2): outer src-tile phase loop ----------
// All co-resident waves sweep tile 0..6 in order; tile slice = 16384 rows
// = 2 MB bf16 -> L2-resident per XCD, so row reads become mostly L2 hits.
template <bool OUT_BF16>
__global__ __launch_bounds__(256) void gather_tiled(
        const ushort* __restrict__ h, const uint* __restrict__ edges,
        const int* __restrict__ tptr, void* __restrict__ out_v, int n_nodes) {
    int wv = blockIdx.x * 4 + (threadIdx.x >> 6);
    int n0 = __builtin_amdgcn_readfirstlane(wv * NPW);
    if (n0 >= n_nodes) return;
    int f = threadIdx.x & 63;
    int nlim = min(NPW, n_nodes - n0);

    float acc[NPW] = {0.f, 0.f, 0.f, 0.f, 0.f, 0.f, 0.f, 0.f};
    for (int tl = 0; tl < NTILES; ++tl) {
        const int* tp0 = tptr + (size_t)tl * (n_nodes + 1) + n0;
        const int* tp1 = tptr + (size_t)(tl + 1) * (n_nodes + 1) + n0;
        #pragma unroll
        for (int ni = 0; ni < NPW; ++ni) {
            if (ni >= nlim) break;
            int beg = __builtin_amdgcn_readfirstlane(tp0[ni]);
            int end = __builtin_amdgcn_readfirstlane(tp1[ni]);
            float a = acc[ni];
            for (int j = beg; j < end; ++j) {
                uint ev = edges[j];
                a += wq2f(ev) * bf2f(h[((size_t)(ev >> 15) << 6) + f]);
            }
            acc[ni] = a;
        }
    }
    #pragma unroll
    for (int ni = 0; ni < NPW; ++ni) {
        if (ni >= nlim) break;
        size_t o = ((size_t)(n0 + ni) << 6) + f;
        if (OUT_BF16) ((ushort*)out_v)[o] = f2bf(acc[ni]);
        else          ((float*)out_v)[o]  = acc[ni];
    }
}

extern "C" void kernel_launch(void* const* d_in, const int* in_sizes, int n_in,
                              void* d_out, int out_size, void* d_ws, size_t ws_size,
                              hipStream_t stream) {
    const float* x   = (const float*)d_in[0];
    const float* ew  = (const float*)d_in[1];
    const int*   src = (const int*)d_in[2];
    const int*   dst = (const int*)d_in[3];
    float* out = (float*)d_out;

    const int n_nodes = in_sizes[0] / D_FEAT;   // 100000
    const int n_edges = in_sizes[1];            // 3200000
    const int nbuck   = (n_nodes + BSIZE - 1) >> BSHIFT;   // 196
    const int n_feat_total = n_nodes * D_FEAT;

    const size_t ed4_bytes = (size_t)n_edges * 4;          // 12.8 MB
    const size_t bf_bytes  = (size_t)n_feat_total * 2;     // 12.8 MB

    // workspace: [region0 (25.6MB): interp(12.8)+interd(6.4) -> later x_bf(12.8)+buf1(12.8)]
    //            [edges 12.8MB][tptr 8*(N+1)][bcount(256)+bcursor(256)]
    char* wp = (char*)d_ws;
    uint*   interp = (uint*)wp;
    ushort* interd = (ushort*)(wp + ed4_bytes);
    ushort* x_bf   = (ushort*)wp;
    ushort* buf1   = (ushort*)(wp + bf_bytes);
    wp += 2 * bf_bytes;                          // 25.6 MB region0
    uint* edges    = (uint*)wp;                  wp += ed4_bytes;
    int*  tptr     = (int*)wp;                   wp += (size_t)8 * (n_nodes + 1) * 4;
    int*  bcount   = (int*)wp;                   wp += 256 * 4;
    int*  bcursor  = (int*)wp;

    // --- build dst-sorted, src-tile-ordered CSR ---
    hipMemsetAsync(bcount, 0, 512 * 4, stream);             // bcount + bcursor
    bucket_hist<<<512, 256, 0, stream>>>(dst, bcount, n_edges);
    partition_kernel<<<(n_edges + CHUNK - 1) / CHUNK, 256, 0, stream>>>(
        src, dst, ew, bcount, bcursor, interp, interd, n_edges);
    finalize_kernel<<<nbuck, BSIZE, 0, stream>>>(
        interp, interd, bcount, edges, tptr, n_nodes, n_edges);

    // --- convert x to bf16 (region0 now free) ---
    cvt_bf16<<<1024, 256, 0, stream>>>(x, x_bf, n_feat_total / 4);

    // --- 3 gather hops: x_bf -> buf1 -> x_bf -> out(f32); tiled A/B on hop 2 ---
    const int grd = ((n_nodes + NPW * 4 - 1) / (NPW * 4));
    gather_hop  <true ><<<grd, 256, 0, stream>>>(x_bf, edges, tptr, buf1, n_nodes);
    gather_tiled<true ><<<grd, 256, 0, stream>>>(buf1, edges, tptr, x_bf, n_nodes);
    gather_hop  <false><<<grd, 256, 0, stream>>>(x_bf, edges, tptr, out,  n_nodes);
}

// Round 16
// 335.184 us; speedup vs baseline: 1.3127x; 1.3127x over previous
//
#include <hip/hip_runtime.h>

#define D_FEAT 64
#define CHUNK 8192
#define BSHIFT 9
#define BSIZE 512
#define NPW 8

typedef unsigned int uint;
typedef unsigned short ushort;

static __device__ __forceinline__ ushort f2bf(float f) {
    uint u = __float_as_uint(f);
    uint r = (u + 0x7fffu + ((u >> 16) & 1u)) >> 16;   // RNE
    return (ushort)r;
}
static __device__ __forceinline__ float bf2f(ushort b) {
    return __uint_as_float(((uint)b) << 16);
}
static __device__ __forceinline__ float wq2f(uint ev) {
    return (float)(ev & 32767u) * (1.0f / 32768.0f) + (1.0f / 65536.0f);
}

// ---------- Phase A (fused): bucket histogram + x->bf16 convert (independent work) ----------
__global__ __launch_bounds__(256) void hist_cvt(
        const int* __restrict__ dst, int* __restrict__ bcount,
        const float* __restrict__ x, ushort* __restrict__ x_bf,
        int n_edges, int nf4) {
    __shared__ int h[256];
    h[threadIdx.x] = 0;
    __syncthreads();
    int tid = blockIdx.x * blockDim.x + threadIdx.x;
    int stride = gridDim.x * blockDim.x;
    int n4 = n_edges >> 2;
    for (int i = tid; i < n4; i += stride) {
        int4 d = ((const int4*)dst)[i];
        atomicAdd(&h[d.x >> BSHIFT], 1);
        atomicAdd(&h[d.y >> BSHIFT], 1);
        atomicAdd(&h[d.z >> BSHIFT], 1);
        atomicAdd(&h[d.w >> BSHIFT], 1);
    }
    for (int i = (n4 << 2) + tid; i < n_edges; i += stride)
        atomicAdd(&h[dst[i] >> BSHIFT], 1);
    // independent: convert features while hist atomics drain
    for (int i = tid; i < nf4; i += stride) {
        float4 v = ((const float4*)x)[i];
        ushort4 o;
        o.x = f2bf(v.x); o.y = f2bf(v.y); o.z = f2bf(v.z); o.w = f2bf(v.w);
        ((ushort4*)x_bf)[i] = o;
    }
    __syncthreads();
    int v = h[threadIdx.x];
    if (v) atomicAdd(&bcount[threadIdx.x], v);
}

// ---------- Phase C: rank-staged counting sort by bucket ----------
// Stages only a 13-bit permutation (16 KB LDS -> ~7 WG/CU vs 2 for record
// staging); flush re-gathers src/w/dst (L2-hot) by permuted index and writes
// bucket-contiguous coalesced runs.
__global__ __launch_bounds__(256) void partition_kernel(
        const int* __restrict__ src, const int* __restrict__ dst,
        const float* __restrict__ w, const int* __restrict__ bcount,
        int* __restrict__ bcursor,
        uint* __restrict__ interp, ushort* __restrict__ interd, int n_edges) {
    __shared__ int hist[256];
    __shared__ int lofs[256];
    __shared__ int cur[256];
    __shared__ int gbase[256];
    __shared__ int scn[256];
    __shared__ ushort perm[CHUNK];       // 16 KB
    int t = threadIdx.x;
    int beg = blockIdx.x * CHUNK;
    int end = min(beg + CHUNK, n_edges);
    int cnt = end - beg;

    hist[t] = 0;
    __syncthreads();
    for (int i = beg + t; i < end; i += 256)
        atomicAdd(&hist[dst[i] >> BSHIFT], 1);
    __syncthreads();
    // chunk-local exclusive scan
    int v = hist[t];
    scn[t] = v;
    __syncthreads();
    for (int off = 1; off < 256; off <<= 1) {
        int u = (t >= off) ? scn[t - off] : 0;
        __syncthreads();
        scn[t] += u;
        __syncthreads();
    }
    int excl = scn[t] - v;
    lofs[t] = excl;
    cur[t]  = excl;
    __syncthreads();
    // rank pass: 2B LDS scatter (~2 lanes/bank, free)
    for (int i = beg + t; i < end; i += 256) {
        int b = dst[i] >> BSHIFT;
        int p = atomicAdd(&cur[b], 1);
        perm[p] = (ushort)(i - beg);
    }
    __syncthreads();
    // global bucket bases: local scan of bcount + cursor reservation
    int bcv = bcount[t];
    scn[t] = bcv;
    __syncthreads();
    for (int off = 1; off < 256; off <<= 1) {
        int u = (t >= off) ? scn[t - off] : 0;
        __syncthreads();
        scn[t] += u;
        __syncthreads();
    }
    int gbb = scn[t] - bcv;
    if (hist[t]) gbase[t] = gbb + atomicAdd(&bcursor[t], hist[t]);
    __syncthreads();
    // flush: staged order is bucket-sorted -> contiguous runs; records built
    // from L2-hot re-gather of src/w/dst
    for (int i = t; i < cnt; i += 256) {
        int e = beg + perm[i];
        int d = dst[e];
        int b = d >> BSHIFT;
        float wf = w[e];
        uint wq = (uint)(wf * 32768.0f);
        if (wq > 32767u) wq = 32767u;
        int pos = gbase[b] + (i - lofs[b]);
        interp[pos] = ((uint)src[e] << 15) | wq;
        interd[pos] = (ushort)(d & (BSIZE - 1));
    }
}

// ---------- Phase D: per-bucket counting sort by node; emits row_ptr + packed edges ----------
__global__ __launch_bounds__(512) void finalize_kernel(
        const uint* __restrict__ interp, const ushort* __restrict__ interd,
        const int* __restrict__ bcount, uint* __restrict__ edges,
        int* __restrict__ row_ptr, int n_nodes, int n_edges) {
    __shared__ int hist[BSIZE];
    __shared__ int cur[BSIZE];
    __shared__ int scn[256];
    int b = blockIdx.x;
    int t = threadIdx.x;

    if (t < 256) scn[t] = bcount[t];
    __syncthreads();
    for (int off = 1; off < 256; off <<= 1) {
        int u = (t < 256 && t >= off) ? scn[t - off] : 0;
        __syncthreads();
        if (t < 256) scn[t] += u;
        __syncthreads();
    }
    int base = (b == 0) ? 0 : scn[b - 1];
    int cnt  = scn[b] - base;

    hist[t] = 0;
    __syncthreads();
    for (int i = t; i < cnt; i += BSIZE)
        atomicAdd(&hist[interd[base + i]], 1);     // 2B plane read only
    __syncthreads();
    int v = hist[t];
    cur[t] = v;
    __syncthreads();
    for (int off = 1; off < BSIZE; off <<= 1) {
        int u = (t >= off) ? cur[t - off] : 0;
        __syncthreads();
        cur[t] += u;
        __syncthreads();
    }
    int excl = cur[t] - v;
    int node = (b << BSHIFT) + t;
    if (node < n_nodes) row_ptr[node] = base + excl;
    if (b == 0 && t == 0) row_ptr[n_nodes] = n_edges;
    __syncthreads();
    cur[t] = excl;
    __syncthreads();
    for (int i = t; i < cnt; i += BSIZE) {
        int dlo = interd[base + i];
        int p = atomicAdd(&cur[dlo], 1);
        edges[base + p] = interp[base + i];
    }
}

// ---------- gather hop (R9 known-good): one wave per NPW nodes; lane = feature ----------
template <bool OUT_BF16>
__global__ __launch_bounds__(256) void gather_hop(
        const ushort* __restrict__ h, const uint* __restrict__ edges,
        const int* __restrict__ row_ptr, void* __restrict__ out_v, int n_nodes) {
    int wv = blockIdx.x * 4 + (threadIdx.x >> 6);
    int n0 = __builtin_amdgcn_readfirstlane(wv * NPW);
    if (n0 >= n_nodes) return;
    int f = threadIdx.x & 63;

    int rp[NPW + 1];
    #pragma unroll
    for (int i = 0; i <= NPW; ++i)
        rp[i] = row_ptr[min(n0 + i, n_nodes)];

    #pragma unroll
    for (int ni = 0; ni < NPW; ++ni) {
        int node = n0 + ni;
        if (node >= n_nodes) break;
        int beg = __builtin_amdgcn_readfirstlane(rp[ni]);
        int end = __builtin_amdgcn_readfirstlane(rp[ni + 1]);
        float acc = 0.0f;
        int j = beg;
        for (; j + 8 <= end; j += 8) {
            #pragma unroll
            for (int k = 0; k < 8; ++k) {
                uint ev = edges[j + k];
                acc += wq2f(ev) * bf2f(h[((size_t)(ev >> 15) << 6) + f]);
            }
        }
        for (; j < end; ++j) {
            uint ev = edges[j];
            acc += wq2f(ev) * bf2f(h[((size_t)(ev >> 15) << 6) + f]);
        }
        size_t o = ((size_t)node << 6) + f;
        if (OUT_BF16) ((ushort*)out_v)[o] = f2bf(acc);
        else          ((float*)out_v)[o]  = acc;
    }
}

extern "C" void kernel_launch(void* const* d_in, const int* in_sizes, int n_in,
                              void* d_out, int out_size, void* d_ws, size_t ws_size,
                              hipStream_t stream) {
    const float* x   = (const float*)d_in[0];
    const float* ew  = (const float*)d_in[1];
    const int*   src = (const int*)d_in[2];
    const int*   dst = (const int*)d_in[3];
    float* out = (float*)d_out;

    const int n_nodes = in_sizes[0] / D_FEAT;   // 100000
    const int n_edges = in_sizes[1];            // 3200000
    const int nbuck   = (n_nodes + BSIZE - 1) >> BSHIFT;   // 196
    const int n_feat_total = n_nodes * D_FEAT;

    const size_t ed4_bytes = (size_t)n_edges * 4;          // 12.8 MB
    const size_t ed2_bytes = (size_t)n_edges * 2;          // 6.4 MB
    const size_t bf_bytes  = (size_t)n_feat_total * 2;     // 12.8 MB

    // layout (x_bf coexists with build intermediates; buf1 aliases interp+interd):
    // [A: interp 12.8 | later buf1][B: interd 6.4][C: x_bf 12.8][D: edges 12.8][E: row_ptr+counters]
    char* wp = (char*)d_ws;
    uint*   interp = (uint*)wp;
    ushort* buf1   = (ushort*)wp;                 wp += ed4_bytes;
    ushort* interd = (ushort*)wp;                 wp += ed2_bytes;
    ushort* x_bf   = (ushort*)wp;                 wp += bf_bytes;
    uint*   edges  = (uint*)wp;                   wp += ed4_bytes;
    int*    row_ptr= (int*)wp;                    wp += (size_t)(n_nodes + 1) * 4;
    int*    bcount = (int*)wp;                    wp += 256 * 4;
    int*    bcursor= (int*)wp;

    // --- build dst-sorted CSR + convert (fused) ---
    hipMemsetAsync(bcount, 0, 512 * 4, stream);             // bcount + bcursor
    hist_cvt<<<512, 256, 0, stream>>>(dst, bcount, x, x_bf, n_edges, n_feat_total / 4);
    partition_kernel<<<(n_edges + CHUNK - 1) / CHUNK, 256, 0, stream>>>(
        src, dst, ew, bcount, bcursor, interp, interd, n_edges);
    finalize_kernel<<<nbuck, BSIZE, 0, stream>>>(
        interp, interd, bcount, edges, row_ptr, n_nodes, n_edges);

    // --- 3 gather hops: x_bf -> buf1 -> x_bf -> out(f32) ---
    const int grd = ((n_nodes + NPW * 4 - 1) / (NPW * 4));
    gather_hop<true ><<<grd, 256, 0, stream>>>(x_bf, edges, row_ptr, buf1, n_nodes);
    gather_hop<true ><<<grd, 256, 0, stream>>>(buf1, edges, row_ptr, x_bf, n_nodes);
    gather_hop<false><<<grd, 256, 0, stream>>>(x_bf, edges, row_ptr, out,  n_nodes);
}

// Round 17
// 330.398 us; speedup vs baseline: 1.3317x; 1.0145x over previous
//
#include <hip/hip_runtime.h>

#define D_FEAT 64
#define CHUNK 8192
#define BSHIFT 9
#define BSIZE 512
#define NPW 8

typedef unsigned int uint;
typedef unsigned short ushort;

static __device__ __forceinline__ ushort f2bf(float f) {
    uint u = __float_as_uint(f);
    uint r = (u + 0x7fffu + ((u >> 16) & 1u)) >> 16;   // RNE
    return (ushort)r;
}
static __device__ __forceinline__ float bf2f(ushort b) {
    return __uint_as_float(((uint)b) << 16);
}
static __device__ __forceinline__ float wq2f(uint ev) {
    return (float)(ev & 32767u) * (1.0f / 32768.0f) + (1.0f / 65536.0f);
}

// ---------- Phase A (fused): bucket histogram + x->bf16 convert ----------
__global__ __launch_bounds__(256) void hist_cvt(
        const int* __restrict__ dst, int* __restrict__ bcount,
        const float* __restrict__ x, ushort* __restrict__ x_bf,
        int n_edges, int nf4) {
    __shared__ int h[256];
    h[threadIdx.x] = 0;
    __syncthreads();
    int tid = blockIdx.x * blockDim.x + threadIdx.x;
    int stride = gridDim.x * blockDim.x;
    int n4 = n_edges >> 2;
    for (int i = tid; i < n4; i += stride) {
        int4 d = ((const int4*)dst)[i];
        atomicAdd(&h[d.x >> BSHIFT], 1);
        atomicAdd(&h[d.y >> BSHIFT], 1);
        atomicAdd(&h[d.z >> BSHIFT], 1);
        atomicAdd(&h[d.w >> BSHIFT], 1);
    }
    for (int i = (n4 << 2) + tid; i < n_edges; i += stride)
        atomicAdd(&h[dst[i] >> BSHIFT], 1);
    // independent: convert features while hist atomics drain
    for (int i = tid; i < nf4; i += stride) {
        float4 v = ((const float4*)x)[i];
        ushort4 o;
        o.x = f2bf(v.x); o.y = f2bf(v.y); o.z = f2bf(v.z); o.w = f2bf(v.w);
        ((ushort4*)x_bf)[i] = o;
    }
    __syncthreads();
    int v = h[threadIdx.x];
    if (v) atomicAdd(&bcount[threadIdx.x], v);
}

// ---------- Phase B: scan 256 bucket counts -> bbase, bcursor ----------
__global__ void bucket_scan(const int* __restrict__ bcount, int* __restrict__ bbase,
                            int* __restrict__ bcursor) {
    __shared__ int s[256];
    int t = threadIdx.x;
    int v = bcount[t];
    s[t] = v;
    __syncthreads();
    for (int off = 1; off < 256; off <<= 1) {
        int u = (t >= off) ? s[t - off] : 0;
        __syncthreads();
        s[t] += u;
        __syncthreads();
    }
    int excl = s[t] - v;
    bbase[t] = excl;
    bcursor[t] = excl;
}

// ---------- Phase C: per-chunk counting sort by bucket (R6-exact: best measured) ----------
__global__ __launch_bounds__(256) void partition_kernel(
        const int* __restrict__ src, const int* __restrict__ dst,
        const float* __restrict__ w, int* __restrict__ bcursor,
        int2* __restrict__ inter, int n_edges) {
    __shared__ int hist[256];
    __shared__ int lofs[256];
    __shared__ int cur[256];
    __shared__ int gbase[256];
    __shared__ int2 buf[CHUNK];          // 64 KB staging
    __shared__ ushort bb[CHUNK];         // 16 KB bucket ids
    int t = threadIdx.x;
    int beg = blockIdx.x * CHUNK;
    int end = min(beg + CHUNK, n_edges);
    int cnt = end - beg;

    hist[t] = 0;
    __syncthreads();
    for (int i = beg + t; i < end; i += 256)
        atomicAdd(&hist[dst[i] >> BSHIFT], 1);
    __syncthreads();
    int v = hist[t];
    lofs[t] = v;
    __syncthreads();
    for (int off = 1; off < 256; off <<= 1) {
        int u = (t >= off) ? lofs[t - off] : 0;
        __syncthreads();
        lofs[t] += u;
        __syncthreads();
    }
    int excl = lofs[t] - v;
    __syncthreads();
    lofs[t] = excl;
    cur[t]  = excl;
    __syncthreads();
    for (int i = beg + t; i < end; i += 256) {
        int d = dst[i];
        int b = d >> BSHIFT;
        int p = atomicAdd(&cur[b], 1);
        buf[p] = make_int2((src[i] << BSHIFT) | (d & (BSIZE - 1)), __float_as_int(w[i]));
        bb[p] = (ushort)b;
    }
    __syncthreads();
    if (hist[t]) gbase[t] = atomicAdd(&bcursor[t], hist[t]);
    __syncthreads();
    // per-edge flush: buf is bucket-sorted -> near-contiguous write runs
    for (int i = t; i < cnt; i += 256) {
        int b = bb[i];
        inter[gbase[b] + (i - lofs[b])] = buf[i];
    }
}

// ---------- Phase D: per-bucket counting sort by node; emits row_ptr + packed 4B edges ----------
__global__ __launch_bounds__(512) void finalize_kernel(
        const int2* __restrict__ inter, const int* __restrict__ bbase,
        const int* __restrict__ bcount, uint* __restrict__ edges,
        int* __restrict__ row_ptr, int n_nodes, int n_edges) {
    __shared__ int hist[BSIZE];
    __shared__ int cur[BSIZE];
    int b = blockIdx.x;
    int t = threadIdx.x;
    int base = bbase[b];
    int cnt  = bcount[b];

    hist[t] = 0;
    __syncthreads();
    for (int i = t; i < cnt; i += BSIZE)
        atomicAdd(&hist[inter[base + i].x & (BSIZE - 1)], 1);
    __syncthreads();
    int v = hist[t];
    cur[t] = v;
    __syncthreads();
    for (int off = 1; off < BSIZE; off <<= 1) {
        int u = (t >= off) ? cur[t - off] : 0;
        __syncthreads();
        cur[t] += u;
        __syncthreads();
    }
    int excl = cur[t] - v;
    int node = (b << BSHIFT) + t;
    if (node < n_nodes) row_ptr[node] = base + excl;
    if (b == 0 && t == 0) row_ptr[n_nodes] = n_edges;
    __syncthreads();
    cur[t] = excl;
    __syncthreads();
    for (int i = t; i < cnt; i += BSIZE) {
        int2 r = inter[base + i];
        int dlo = r.x & (BSIZE - 1);
        int p = atomicAdd(&cur[dlo], 1);
        float wf = __int_as_float(r.y);
        uint wq = (uint)(wf * 32768.0f);
        if (wq > 32767u) wq = 32767u;
        edges[base + p] = ((uint)(r.x >> BSHIFT) << 15) | wq;
    }
}

// ---------- gather hop (R9-exact): one wave per NPW nodes; lane = feature ----------
template <bool OUT_BF16>
__global__ __launch_bounds__(256) void gather_hop(
        const ushort* __restrict__ h, const uint* __restrict__ edges,
        const int* __restrict__ row_ptr, void* __restrict__ out_v, int n_nodes) {
    int wv = blockIdx.x * 4 + (threadIdx.x >> 6);
    int n0 = __builtin_amdgcn_readfirstlane(wv * NPW);
    if (n0 >= n_nodes) return;
    int f = threadIdx.x & 63;

    int rp[NPW + 1];
    #pragma unroll
    for (int i = 0; i <= NPW; ++i)
        rp[i] = row_ptr[min(n0 + i, n_nodes)];

    #pragma unroll
    for (int ni = 0; ni < NPW; ++ni) {
        int node = n0 + ni;
        if (node >= n_nodes) break;
        int beg = __builtin_amdgcn_readfirstlane(rp[ni]);
        int end = __builtin_amdgcn_readfirstlane(rp[ni + 1]);
        float acc = 0.0f;
        int j = beg;
        for (; j + 8 <= end; j += 8) {
            #pragma unroll
            for (int k = 0; k < 8; ++k) {
                uint ev = edges[j + k];
                acc += wq2f(ev) * bf2f(h[((size_t)(ev >> 15) << 6) + f]);
            }
        }
        for (; j < end; ++j) {
            uint ev = edges[j];
            acc += wq2f(ev) * bf2f(h[((size_t)(ev >> 15) << 6) + f]);
        }
        size_t o = ((size_t)node << 6) + f;
        if (OUT_BF16) ((ushort*)out_v)[o] = f2bf(acc);
        else          ((float*)out_v)[o]  = acc;
    }
}

extern "C" void kernel_launch(void* const* d_in, const int* in_sizes, int n_in,
                              void* d_out, int out_size, void* d_ws, size_t ws_size,
                              hipStream_t stream) {
    const float* x   = (const float*)d_in[0];
    const float* ew  = (const float*)d_in[1];
    const int*   src = (const int*)d_in[2];
    const int*   dst = (const int*)d_in[3];
    float* out = (float*)d_out;

    const int n_nodes = in_sizes[0] / D_FEAT;   // 100000
    const int n_edges = in_sizes[1];            // 3200000
    const int nbuck   = (n_nodes + BSIZE - 1) >> BSHIFT;   // 196
    const int n_feat_total = n_nodes * D_FEAT;

    const size_t ed8_bytes = (size_t)n_edges * 8;          // 25.6 MB
    const size_t ed4_bytes = (size_t)n_edges * 4;          // 12.8 MB
    const size_t bf_bytes  = (size_t)n_feat_total * 2;     // 12.8 MB

    // layout: [inter 25.6 (buf1 aliases first 12.8 after finalize)]
    //         [x_bf 12.8][edges 12.8][row_ptr][bcount|bbase|bcursor]
    char* wp = (char*)d_ws;
    int2*   inter  = (int2*)wp;
    ushort* buf1   = (ushort*)wp;                 wp += ed8_bytes;
    ushort* x_bf   = (ushort*)wp;                 wp += bf_bytes;
    uint*   edges  = (uint*)wp;                   wp += ed4_bytes;
    int*    row_ptr= (int*)wp;                    wp += (size_t)(n_nodes + 1) * 4;
    int*    bcount = (int*)wp;                    wp += 256 * 4;
    int*    bbase  = (int*)wp;                    wp += 256 * 4;
    int*    bcursor= (int*)wp;

    // --- build dst-sorted CSR + convert (fused hist) ---
    hipMemsetAsync(bcount, 0, 256 * 4, stream);
    hist_cvt<<<512, 256, 0, stream>>>(dst, bcount, x, x_bf, n_edges, n_feat_total / 4);
    bucket_scan<<<1, 256, 0, stream>>>(bcount, bbase, bcursor);
    partition_kernel<<<(n_edges + CHUNK - 1) / CHUNK, 256, 0, stream>>>(
        src, dst, ew, bcursor, inter, n_edges);
    finalize_kernel<<<nbuck, BSIZE, 0, stream>>>(
        inter, bbase, bcount, edges, row_ptr, n_nodes, n_edges);

    // --- 3 gather hops: x_bf -> buf1 -> x_bf -> out(f32) ---
    const int grd = ((n_nodes + NPW * 4 - 1) / (NPW * 4));
    gather_hop<true ><<<grd, 256, 0, stream>>>(x_bf, edges, row_ptr, buf1, n_nodes);
    gather_hop<true ><<<grd, 256, 0, stream>>>(buf1, edges, row_ptr, x_bf, n_nodes);
    gather_hop<false><<<grd, 256, 0, stream>>>(x_bf, edges, row_ptr, out,  n_nodes);
}